// Round 14
// baseline (469.472 us; speedup 1.0000x reference)
//
#include <hip/hip_runtime.h>

// HeteroConv copy_u + segment_sum.
// R2-R13 ladder: 858 -> 104.5us. Established facts: return-atomics run at a
// flat ~23G/s device rate (R7/R8/R9: occupancy & padding no-ops); NON-return
// atomics ~75G/s (R1); accum is gather-traffic bound (R10/R11); bf16 halves
// gather traffic (R12); scattered 4B stores line-amplify to ~64MB (R13).
// R14 (this): binned scatter with LDS-local ranking -- per-edge return
// atomics ELIMINATED. bin = dst>>8 (256 dsts). bin_hist (LDS hist + 96K
// non-return flush) -> bin_scan -> bin_scatter (ONE return atomic per
// (block,bin) range reservation + LDS return atomics for ranks; packed
// (dlocal<<20)|s output, 4MB L2-resident) -> accum_bin (block=bin, LDS f32
// accumulators stride-65 anti-bank-conflict, exact, no spill).

#define SCAN_T 256
#define SCAN_SEQ 16
#define SCAN_ELEMS (SCAN_T * SCAN_SEQ)

#define DPB 256          // dsts per bin
#define BIN_SHIFT 8
#define EPB 4096         // edges per bin_hist/bin_scatter block (512 thr x 8)

__device__ __forceinline__ unsigned short f2bf(float f) {
    unsigned u = __float_as_uint(f);
    unsigned r = u + 0x7FFFu + ((u >> 16) & 1u);   // round-to-nearest-even
    return (unsigned short)(r >> 16);
}
__device__ __forceinline__ unsigned pack2(float lo, float hi) {
    return (unsigned)f2bf(lo) | ((unsigned)f2bf(hi) << 16);
}

// ---- phase 0: src_emb f32 -> packed bf16 rows (128B/row) ----
__global__ void convert_bf16_kernel(const float4* __restrict__ src4,
                                    uint4* __restrict__ srcb, long n8) {
    long t = (long)blockIdx.x * blockDim.x + threadIdx.x;
    if (t >= n8) return;
    float4 a = src4[t * 2];
    float4 b = src4[t * 2 + 1];
    uint4 o;
    o.x = pack2(a.x, a.y);
    o.y = pack2(a.z, a.w);
    o.z = pack2(b.x, b.y);
    o.w = pack2(b.z, b.w);
    srcb[t] = o;
}

// ---- tier-0 phase 1: per-block LDS bin histogram, non-return flush ----
__global__ void bin_hist_kernel(const int* __restrict__ edst,
                                int* __restrict__ binCounts,
                                int nbins, int n) {
    __shared__ int lc[1024];
    int t = threadIdx.x;
    for (int k = t; k < nbins; k += blockDim.x) lc[k] = 0;
    __syncthreads();

    int i0 = blockIdx.x * EPB + t * 8;
    if (i0 + 7 < n) {
        int4 d0 = *reinterpret_cast<const int4*>(edst + i0);
        int4 d1 = *reinterpret_cast<const int4*>(edst + i0 + 4);
        atomicAdd(&lc[d0.x >> BIN_SHIFT], 1);
        atomicAdd(&lc[d0.y >> BIN_SHIFT], 1);
        atomicAdd(&lc[d0.z >> BIN_SHIFT], 1);
        atomicAdd(&lc[d0.w >> BIN_SHIFT], 1);
        atomicAdd(&lc[d1.x >> BIN_SHIFT], 1);
        atomicAdd(&lc[d1.y >> BIN_SHIFT], 1);
        atomicAdd(&lc[d1.z >> BIN_SHIFT], 1);
        atomicAdd(&lc[d1.w >> BIN_SHIFT], 1);
    } else {
        for (int k = 0; k < 8; ++k) {
            int i = i0 + k;
            if (i < n) atomicAdd(&lc[edst[i] >> BIN_SHIFT], 1);
        }
    }
    __syncthreads();
    for (int k = t; k < nbins; k += blockDim.x) {
        int c = lc[k];
        if (c > 0) atomicAdd(&binCounts[k], c);   // non-returning: fast path
    }
}

// ---- tier-0 phase 2: scan bin counts -> bases (in place) + cursor ----
__global__ void bin_scan_kernel(int* __restrict__ binOff,   // [nbins+1]
                                int* __restrict__ cursor,   // [nbins]
                                int nbins) {
    __shared__ int lds[1024];
    int t = threadIdx.x;
    int v = (t < nbins) ? binOff[t] : 0;
    lds[t] = v;
    __syncthreads();
    for (int off = 1; off < 1024; off <<= 1) {
        int u = (t >= off) ? lds[t - off] : 0;
        __syncthreads();
        lds[t] += u;
        __syncthreads();
    }
    if (t < nbins) {
        int base = lds[t] - v;
        binOff[t] = base;
        cursor[t] = base;
    }
    if (t == 1023) binOff[nbins] = lds[t];   // total = n_edges
}

// ---- tier-0 phase 3: scatter into bins; one return atomic per (block,bin) ----
__global__ void bin_scatter_kernel(const int* __restrict__ esrc,
                                   const int* __restrict__ edst,
                                   int* __restrict__ cursor,
                                   int* __restrict__ packed,
                                   int nbins, int n) {
    __shared__ int lc[1024];     // per-block bin counts
    __shared__ int lbase[1024];  // reserved global base per bin
    __shared__ int lrank[1024];  // per-edge local rank counter
    int t = threadIdx.x;
    for (int k = t; k < nbins; k += blockDim.x) { lc[k] = 0; lrank[k] = 0; }
    __syncthreads();

    int i0 = blockIdx.x * EPB + t * 8;
    bool fast = (i0 + 7 < n);

    if (fast) {
        int4 d0 = *reinterpret_cast<const int4*>(edst + i0);
        int4 d1 = *reinterpret_cast<const int4*>(edst + i0 + 4);
        atomicAdd(&lc[d0.x >> BIN_SHIFT], 1);
        atomicAdd(&lc[d0.y >> BIN_SHIFT], 1);
        atomicAdd(&lc[d0.z >> BIN_SHIFT], 1);
        atomicAdd(&lc[d0.w >> BIN_SHIFT], 1);
        atomicAdd(&lc[d1.x >> BIN_SHIFT], 1);
        atomicAdd(&lc[d1.y >> BIN_SHIFT], 1);
        atomicAdd(&lc[d1.z >> BIN_SHIFT], 1);
        atomicAdd(&lc[d1.w >> BIN_SHIFT], 1);
    } else {
        for (int k = 0; k < 8; ++k) {
            int i = i0 + k;
            if (i < n) atomicAdd(&lc[edst[i] >> BIN_SHIFT], 1);
        }
    }
    __syncthreads();

    // one global RETURN atomic per nonzero (block, bin): reserves the range
    for (int k = t; k < nbins; k += blockDim.x) {
        int c = lc[k];
        if (c > 0) lbase[k] = atomicAdd(&cursor[k], c);
    }
    __syncthreads();

    if (fast) {
        int4 s0 = *reinterpret_cast<const int4*>(esrc + i0);
        int4 s1 = *reinterpret_cast<const int4*>(esrc + i0 + 4);
        int4 d0 = *reinterpret_cast<const int4*>(edst + i0);
        int4 d1 = *reinterpret_cast<const int4*>(edst + i0 + 4);
        {
            int k = d0.x >> BIN_SHIFT, r = atomicAdd(&lrank[k], 1);
            packed[lbase[k] + r] = ((d0.x & (DPB - 1)) << 20) | s0.x;
        }
        {
            int k = d0.y >> BIN_SHIFT, r = atomicAdd(&lrank[k], 1);
            packed[lbase[k] + r] = ((d0.y & (DPB - 1)) << 20) | s0.y;
        }
        {
            int k = d0.z >> BIN_SHIFT, r = atomicAdd(&lrank[k], 1);
            packed[lbase[k] + r] = ((d0.z & (DPB - 1)) << 20) | s0.z;
        }
        {
            int k = d0.w >> BIN_SHIFT, r = atomicAdd(&lrank[k], 1);
            packed[lbase[k] + r] = ((d0.w & (DPB - 1)) << 20) | s0.w;
        }
        {
            int k = d1.x >> BIN_SHIFT, r = atomicAdd(&lrank[k], 1);
            packed[lbase[k] + r] = ((d1.x & (DPB - 1)) << 20) | s1.x;
        }
        {
            int k = d1.y >> BIN_SHIFT, r = atomicAdd(&lrank[k], 1);
            packed[lbase[k] + r] = ((d1.y & (DPB - 1)) << 20) | s1.y;
        }
        {
            int k = d1.z >> BIN_SHIFT, r = atomicAdd(&lrank[k], 1);
            packed[lbase[k] + r] = ((d1.z & (DPB - 1)) << 20) | s1.z;
        }
        {
            int k = d1.w >> BIN_SHIFT, r = atomicAdd(&lrank[k], 1);
            packed[lbase[k] + r] = ((d1.w & (DPB - 1)) << 20) | s1.w;
        }
    } else {
        for (int kk = 0; kk < 8; ++kk) {
            int i = i0 + kk;
            if (i < n) {
                int d = edst[i];
                int k = d >> BIN_SHIFT;
                int r = atomicAdd(&lrank[k], 1);
                packed[lbase[k] + r] = ((d & (DPB - 1)) << 20) | esrc[i];
            }
        }
    }
}

// ---- tier-0 phase 4: per-bin accumulation into LDS f32, exact ----
// block = bin. LDS acc[256 dsts][65] (stride 65 -> LDS atomic adds spread
// across banks). Wave64 = 8 groups x 8 lanes; 32 edge slots per block.
// Lane q reads uint4 q of the 128B bf16 row; 8 ds-atomic f32 adds per lane.
// All loads direct (broadcast via same-address load, NO shfl).
__global__ void accum_bin_kernel(const uint4* __restrict__ srcb,
                                 const int* __restrict__ binOff,
                                 const int* __restrict__ packed,
                                 float4* __restrict__ out4, int n_dst) {
    __shared__ float acc[DPB * 65];
    int t = threadIdx.x;
    for (int u = t; u < DPB * 65; u += blockDim.x) acc[u] = 0.f;
    __syncthreads();

    int b = blockIdx.x;
    int start = binOff[b];
    int end = binOff[b + 1];

    int lane = t & 63;
    int w = t >> 6;            // wave 0..3
    int g = lane >> 3;         // group 0..7
    int q = lane & 7;          // uint4 index within row
    int slot = w * 8 + g;      // 0..31

    for (int j = start + slot; j < end; j += 32) {
        int p = packed[j];                       // 8-lane broadcast load
        int s = p & 0xFFFFF;
        int dl = (p >> 20) & (DPB - 1);
        uint4 v = srcb[(size_t)s * 8 + q];
        float* ar = &acc[dl * 65 + q * 8];
        atomicAdd(&ar[0], __uint_as_float(v.x << 16));
        atomicAdd(&ar[1], __uint_as_float(v.x & 0xFFFF0000u));
        atomicAdd(&ar[2], __uint_as_float(v.y << 16));
        atomicAdd(&ar[3], __uint_as_float(v.y & 0xFFFF0000u));
        atomicAdd(&ar[4], __uint_as_float(v.z << 16));
        atomicAdd(&ar[5], __uint_as_float(v.z & 0xFFFF0000u));
        atomicAdd(&ar[6], __uint_as_float(v.w << 16));
        atomicAdd(&ar[7], __uint_as_float(v.w & 0xFFFF0000u));
    }
    __syncthreads();

    int dstBase = b << BIN_SHIFT;
    for (int u = t; u < DPB * 16; u += blockDim.x) {
        int dr = u >> 4;
        int c = u & 15;
        int dd = dstBase + dr;
        if (dd < n_dst) {
            const float* ap = &acc[dr * 65 + c * 4];
            out4[(size_t)dd * 16 + c] = make_float4(ap[0], ap[1], ap[2], ap[3]);
        }
    }
}

// ================= proven R12 pipeline (fallback tiers) =================

__global__ void hist_rank_kernel(const int* __restrict__ edst,
                                 int* __restrict__ counts,
                                 int* __restrict__ rank, int n) {
    int i = blockIdx.x * blockDim.x + threadIdx.x;
    if (i < n) {
        int old = atomicAdd(&counts[edst[i]], 1);
        if (rank) rank[i] = old;
    }
}

__global__ void scan_blocks_kernel(const int* __restrict__ counts,
                                   int* __restrict__ offsets,
                                   int* __restrict__ block_sums, int n) {
    __shared__ int lds[SCAN_T];
    int t = threadIdx.x;
    int base = blockIdx.x * SCAN_ELEMS + t * SCAN_SEQ;

    int local[SCAN_SEQ];
    int s = 0;
    for (int k = 0; k < SCAN_SEQ; ++k) {
        int i = base + k;
        int v = (i < n) ? counts[i] : 0;
        local[k] = s;
        s += v;
    }
    lds[t] = s;
    __syncthreads();
    for (int off = 1; off < SCAN_T; off <<= 1) {
        int v = (t >= off) ? lds[t - off] : 0;
        __syncthreads();
        lds[t] += v;
        __syncthreads();
    }
    int thread_base = (t == 0) ? 0 : lds[t - 1];
    for (int k = 0; k < SCAN_SEQ; ++k) {
        int i = base + k;
        if (i < n) offsets[i] = thread_base + local[k];
    }
    if (t == SCAN_T - 1) block_sums[blockIdx.x] = lds[t];
}

__global__ void scan_sums_kernel(int* __restrict__ block_sums,
                                 int* __restrict__ total_out, int nblocks) {
    __shared__ int lds[1024];
    int t = threadIdx.x;
    int v = (t < nblocks) ? block_sums[t] : 0;
    lds[t] = v;
    __syncthreads();
    for (int off = 1; off < 1024; off <<= 1) {
        int u = (t >= off) ? lds[t - off] : 0;
        __syncthreads();
        lds[t] += u;
        __syncthreads();
    }
    if (t < nblocks) block_sums[t] = lds[t] - v;
    if (t == 1023) *total_out = lds[t];
}

__global__ void scatter_rank_kernel(const int* __restrict__ esrc,
                                    const int* __restrict__ edst,
                                    const int* __restrict__ rank,
                                    const int* __restrict__ offsets,
                                    const int* __restrict__ bases,
                                    int* __restrict__ sorted_src, int n) {
    int i = (blockIdx.x * blockDim.x + threadIdx.x) * 4;
    if (i + 3 < n) {
        int4 s = *reinterpret_cast<const int4*>(esrc + i);
        int4 d = *reinterpret_cast<const int4*>(edst + i);
        int4 r = *reinterpret_cast<const int4*>(rank + i);
        sorted_src[offsets[d.x] + bases[d.x >> 12] + r.x] = s.x;
        sorted_src[offsets[d.y] + bases[d.y >> 12] + r.y] = s.y;
        sorted_src[offsets[d.z] + bases[d.z >> 12] + r.z] = s.z;
        sorted_src[offsets[d.w] + bases[d.w >> 12] + r.w] = s.w;
    } else {
        for (int k = 0; k < 4; ++k) {
            int ii = i + k;
            if (ii < n) {
                int d = edst[ii];
                sorted_src[offsets[d] + bases[d >> 12] + rank[ii]] = esrc[ii];
            }
        }
    }
}

__global__ void accum_bf16_kernel(const uint4* __restrict__ srcb,
                                  const int* __restrict__ offsets,
                                  const int* __restrict__ bases,
                                  const int* __restrict__ sorted_src,
                                  float4* __restrict__ out4, int n_dst) {
    int node = blockIdx.x * (blockDim.x >> 6) + (threadIdx.x >> 6);
    if (node >= n_dst) return;
    int lane = threadIdx.x & 63;
    int g = lane >> 3;
    int q = lane & 7;

    int start = offsets[node] + bases[node >> 12];
    int end = (node + 1 == n_dst)
                  ? offsets[n_dst]
                  : offsets[node + 1] + bases[(node + 1) >> 12];

    float a0 = 0.f, a1 = 0.f, a2 = 0.f, a3 = 0.f;
    float a4 = 0.f, a5 = 0.f, a6 = 0.f, a7 = 0.f;

    for (int j = start + g; j < end; j += 8) {
        int s = sorted_src[j];
        uint4 v = srcb[(size_t)s * 8 + q];
        a0 += __uint_as_float(v.x << 16);
        a1 += __uint_as_float(v.x & 0xFFFF0000u);
        a2 += __uint_as_float(v.y << 16);
        a3 += __uint_as_float(v.y & 0xFFFF0000u);
        a4 += __uint_as_float(v.z << 16);
        a5 += __uint_as_float(v.z & 0xFFFF0000u);
        a6 += __uint_as_float(v.w << 16);
        a7 += __uint_as_float(v.w & 0xFFFF0000u);
    }

#pragma unroll
    for (int off = 8; off < 64; off <<= 1) {
        a0 += __shfl_xor(a0, off);
        a1 += __shfl_xor(a1, off);
        a2 += __shfl_xor(a2, off);
        a3 += __shfl_xor(a3, off);
        a4 += __shfl_xor(a4, off);
        a5 += __shfl_xor(a5, off);
        a6 += __shfl_xor(a6, off);
        a7 += __shfl_xor(a7, off);
    }
    if (g == 0) {
        size_t o = (size_t)node * 16 + q * 2;
        out4[o]     = make_float4(a0, a1, a2, a3);
        out4[o + 1] = make_float4(a4, a5, a6, a7);
    }
}

__global__ void atomic_scatter_kernel(const float* __restrict__ src_emb,
                                      const int* __restrict__ esrc,
                                      const int* __restrict__ edst,
                                      float* __restrict__ out, int n_edges) {
    int tid = blockIdx.x * blockDim.x + threadIdx.x;
    int e = tid >> 4;
    int q = tid & 15;
    if (e >= n_edges) return;
    int s = esrc[e];
    int d = edst[e];
    const float4* srow = reinterpret_cast<const float4*>(src_emb);
    float4 v = srow[(size_t)s * 16 + q];
    float* orow = out + (size_t)d * 64 + (size_t)q * 4;
    atomicAdd(orow + 0, v.x);
    atomicAdd(orow + 1, v.y);
    atomicAdd(orow + 2, v.z);
    atomicAdd(orow + 3, v.w);
}

extern "C" void kernel_launch(void* const* d_in, const int* in_sizes, int n_in,
                              void* d_out, int out_size, void* d_ws, size_t ws_size,
                              hipStream_t stream) {
    const float* src_emb = (const float*)d_in[0];
    const int* edge_src  = (const int*)d_in[1];
    const int* edge_dst  = (const int*)d_in[2];
    float* out = (float*)d_out;

    const int n_edges = in_sizes[1];
    const int n_src   = in_sizes[0] / 64;
    const int n_dst   = out_size / 64;

    const int B = 256;
    long n8 = (long)n_src * 8;
    size_t ws_ints = ws_size / sizeof(int);

    // ---------- tier-0: binned LDS-rank pipeline ----------
    // ints: srcb[n_src*32] | binOff[nbins+1] | cursor[nbins] | packed[E]
    {
        int nbins = (n_dst + DPB - 1) >> BIN_SHIFT;
        size_t srcb_ints = (size_t)n_src * 32;
        size_t need0 = srcb_ints + (size_t)nbins + 1 + nbins + (size_t)n_edges;
        if (n_dst > 0 && n_edges > 0 && n_src > 0 && n_src <= (1 << 20) &&
            nbins <= 1024 && ws_ints >= need0) {
            uint4* srcb  = (uint4*)d_ws;
            int* binOff  = (int*)d_ws + srcb_ints;     // [nbins+1]
            int* cursor  = binOff + nbins + 1;         // [nbins]
            int* packed  = cursor + nbins;             // [n_edges]

            int eblocks = (n_edges + EPB - 1) / EPB;

            convert_bf16_kernel<<<(int)((n8 + B - 1) / B), B, 0, stream>>>(
                reinterpret_cast<const float4*>(src_emb), srcb, n8);
            hipMemsetAsync(binOff, 0, ((size_t)nbins + 1) * sizeof(int), stream);
            bin_hist_kernel<<<eblocks, 512, 0, stream>>>(edge_dst, binOff,
                                                         nbins, n_edges);
            bin_scan_kernel<<<1, 1024, 0, stream>>>(binOff, cursor, nbins);
            bin_scatter_kernel<<<eblocks, 512, 0, stream>>>(edge_src, edge_dst,
                                                            cursor, packed,
                                                            nbins, n_edges);
            accum_bin_kernel<<<nbins, 256, 0, stream>>>(
                srcb, binOff, packed, reinterpret_cast<float4*>(out), n_dst);
            return;
        }
    }

    // ---------- tier-1: R12 bf16 CSR (proven 115.7us) ----------
    const int nscan = (n_dst + SCAN_ELEMS - 1) / SCAN_ELEMS;
    const int egrid4 = (n_edges + 4 * B - 1) / (4 * B);
    const int egrid1 = (n_edges + B - 1) / B;
    const int nodes_per_block = B / 64;
    const int agrid = (n_dst + nodes_per_block - 1) / nodes_per_block;

    size_t off_pad = ((size_t)n_dst + 1 + 3) & ~(size_t)3;
    size_t csr_ints = off_pad + 2 * (size_t)n_edges + nscan;
    size_t need1 = ((size_t)n_src * 32 + csr_ints) * sizeof(int);

    bool csr_ok = (nscan <= 1024) && (n_dst > 0) && (n_dst <= n_edges) &&
                  ((n_edges & 3) == 0);

    if (csr_ok && n_src > 0 && ws_size >= need1) {
        uint4* srcb     = (uint4*)d_ws;
        int* offsets    = (int*)d_ws + (size_t)n_src * 32;
        int* rank       = offsets + off_pad;
        int* sorted_src = rank + n_edges;
        int* block_sums = sorted_src + n_edges;
        int* counts     = sorted_src;

        convert_bf16_kernel<<<(int)((n8 + B - 1) / B), B, 0, stream>>>(
            reinterpret_cast<const float4*>(src_emb), srcb, n8);
        hipMemsetAsync(counts, 0, (size_t)n_dst * sizeof(int), stream);
        hist_rank_kernel<<<egrid1, B, 0, stream>>>(edge_dst, counts, rank, n_edges);
        scan_blocks_kernel<<<nscan, SCAN_T, 0, stream>>>(counts, offsets, block_sums, n_dst);
        scan_sums_kernel<<<1, 1024, 0, stream>>>(block_sums, offsets + n_dst, nscan);
        scatter_rank_kernel<<<egrid4, B, 0, stream>>>(edge_src, edge_dst, rank,
                                                      offsets, block_sums,
                                                      sorted_src, n_edges);
        accum_bf16_kernel<<<agrid, B, 0, stream>>>(
            srcb, offsets, block_sums, sorted_src,
            reinterpret_cast<float4*>(out), n_dst);
        return;
    }

    // ---------- tier-3: direct atomic fallback ----------
    hipMemsetAsync(d_out, 0, (size_t)out_size * sizeof(float), stream);
    int total = n_edges * 16;
    atomic_scatter_kernel<<<(total + 255) / 256, 256, 0, stream>>>(
        src_emb, edge_src, edge_dst, out, n_edges);
}

// Round 15
// 81.414 us; speedup vs baseline: 5.7665x; 5.7665x over previous
//
#include <hip/hip_runtime.h>

// HeteroConv copy_u + segment_sum.
// Ladder: 858 -> 104.5us (R13 best). Facts: per-edge return-atomics = flat
// ~23G/s floor (43us/M); non-return ~75G/s; accum gather is traffic-bound,
// bf16 halves it. R14: bin front-end correct+cheap, but block=bin LDS-f32
// accum was 434us (12% occupancy, 65KB LDS, serial LDS-RMW chains).
// R15 (this): keep bin front-end; NEW bin_sort pass (1KB LDS: 256 counters;
// LDS hist -> 256-scan -> LDS-rank scatter) emits dst-sorted edges + absolute
// offsets; then the PROVEN R12-style parallel accum. Per-edge global return
// atomics: ZERO (only ~96K block-level range reservations).

#define DPB 256          // dsts per bin
#define BIN_SHIFT 8
#define EPB 4096         // edges per bin_hist/bin_scatter block (512 thr x 8)

__device__ __forceinline__ unsigned short f2bf(float f) {
    unsigned u = __float_as_uint(f);
    unsigned r = u + 0x7FFFu + ((u >> 16) & 1u);   // round-to-nearest-even
    return (unsigned short)(r >> 16);
}
__device__ __forceinline__ unsigned pack2(float lo, float hi) {
    return (unsigned)f2bf(lo) | ((unsigned)f2bf(hi) << 16);
}

// ---- phase 0: src_emb f32 -> packed bf16 rows (128B/row) ----
__global__ void convert_bf16_kernel(const float4* __restrict__ src4,
                                    uint4* __restrict__ srcb, long n8) {
    long t = (long)blockIdx.x * blockDim.x + threadIdx.x;
    if (t >= n8) return;
    float4 a = src4[t * 2];
    float4 b = src4[t * 2 + 1];
    uint4 o;
    o.x = pack2(a.x, a.y);
    o.y = pack2(a.z, a.w);
    o.z = pack2(b.x, b.y);
    o.w = pack2(b.z, b.w);
    srcb[t] = o;
}

// ---- phase 1: per-block LDS bin histogram, non-return flush (proven) ----
__global__ void bin_hist_kernel(const int* __restrict__ edst,
                                int* __restrict__ binCounts,
                                int nbins, int n) {
    __shared__ int lc[1024];
    int t = threadIdx.x;
    for (int k = t; k < nbins; k += blockDim.x) lc[k] = 0;
    __syncthreads();

    int i0 = blockIdx.x * EPB + t * 8;
    if (i0 + 7 < n) {
        int4 d0 = *reinterpret_cast<const int4*>(edst + i0);
        int4 d1 = *reinterpret_cast<const int4*>(edst + i0 + 4);
        atomicAdd(&lc[d0.x >> BIN_SHIFT], 1);
        atomicAdd(&lc[d0.y >> BIN_SHIFT], 1);
        atomicAdd(&lc[d0.z >> BIN_SHIFT], 1);
        atomicAdd(&lc[d0.w >> BIN_SHIFT], 1);
        atomicAdd(&lc[d1.x >> BIN_SHIFT], 1);
        atomicAdd(&lc[d1.y >> BIN_SHIFT], 1);
        atomicAdd(&lc[d1.z >> BIN_SHIFT], 1);
        atomicAdd(&lc[d1.w >> BIN_SHIFT], 1);
    } else {
        for (int k = 0; k < 8; ++k) {
            int i = i0 + k;
            if (i < n) atomicAdd(&lc[edst[i] >> BIN_SHIFT], 1);
        }
    }
    __syncthreads();
    for (int k = t; k < nbins; k += blockDim.x) {
        int c = lc[k];
        if (c > 0) atomicAdd(&binCounts[k], c);   // non-returning: fast path
    }
}

// ---- phase 2: scan bin counts -> bases (in place) + cursor (proven) ----
__global__ void bin_scan_kernel(int* __restrict__ binOff,   // [nbins+1]
                                int* __restrict__ cursor,   // [nbins]
                                int nbins) {
    __shared__ int lds[1024];
    int t = threadIdx.x;
    int v = (t < nbins) ? binOff[t] : 0;
    lds[t] = v;
    __syncthreads();
    for (int off = 1; off < 1024; off <<= 1) {
        int u = (t >= off) ? lds[t - off] : 0;
        __syncthreads();
        lds[t] += u;
        __syncthreads();
    }
    if (t < nbins) {
        int base = lds[t] - v;
        binOff[t] = base;
        cursor[t] = base;
    }
    if (t == 1023) binOff[nbins] = lds[t];   // total = n_edges
}

// ---- phase 3: scatter into bin-grouped packed[] (proven) ----
__global__ void bin_scatter_kernel(const int* __restrict__ esrc,
                                   const int* __restrict__ edst,
                                   int* __restrict__ cursor,
                                   int* __restrict__ packed,
                                   int nbins, int n) {
    __shared__ int lc[1024];
    __shared__ int lbase[1024];
    __shared__ int lrank[1024];
    int t = threadIdx.x;
    for (int k = t; k < nbins; k += blockDim.x) { lc[k] = 0; lrank[k] = 0; }
    __syncthreads();

    int i0 = blockIdx.x * EPB + t * 8;
    bool fast = (i0 + 7 < n);

    if (fast) {
        int4 d0 = *reinterpret_cast<const int4*>(edst + i0);
        int4 d1 = *reinterpret_cast<const int4*>(edst + i0 + 4);
        atomicAdd(&lc[d0.x >> BIN_SHIFT], 1);
        atomicAdd(&lc[d0.y >> BIN_SHIFT], 1);
        atomicAdd(&lc[d0.z >> BIN_SHIFT], 1);
        atomicAdd(&lc[d0.w >> BIN_SHIFT], 1);
        atomicAdd(&lc[d1.x >> BIN_SHIFT], 1);
        atomicAdd(&lc[d1.y >> BIN_SHIFT], 1);
        atomicAdd(&lc[d1.z >> BIN_SHIFT], 1);
        atomicAdd(&lc[d1.w >> BIN_SHIFT], 1);
    } else {
        for (int k = 0; k < 8; ++k) {
            int i = i0 + k;
            if (i < n) atomicAdd(&lc[edst[i] >> BIN_SHIFT], 1);
        }
    }
    __syncthreads();

    for (int k = t; k < nbins; k += blockDim.x) {
        int c = lc[k];
        if (c > 0) lbase[k] = atomicAdd(&cursor[k], c);  // ~96K total: cheap
    }
    __syncthreads();

    if (fast) {
        int4 s0 = *reinterpret_cast<const int4*>(esrc + i0);
        int4 s1 = *reinterpret_cast<const int4*>(esrc + i0 + 4);
        int4 d0 = *reinterpret_cast<const int4*>(edst + i0);
        int4 d1 = *reinterpret_cast<const int4*>(edst + i0 + 4);
        { int k = d0.x >> BIN_SHIFT, r = atomicAdd(&lrank[k], 1);
          packed[lbase[k] + r] = ((d0.x & (DPB - 1)) << 20) | s0.x; }
        { int k = d0.y >> BIN_SHIFT, r = atomicAdd(&lrank[k], 1);
          packed[lbase[k] + r] = ((d0.y & (DPB - 1)) << 20) | s0.y; }
        { int k = d0.z >> BIN_SHIFT, r = atomicAdd(&lrank[k], 1);
          packed[lbase[k] + r] = ((d0.z & (DPB - 1)) << 20) | s0.z; }
        { int k = d0.w >> BIN_SHIFT, r = atomicAdd(&lrank[k], 1);
          packed[lbase[k] + r] = ((d0.w & (DPB - 1)) << 20) | s0.w; }
        { int k = d1.x >> BIN_SHIFT, r = atomicAdd(&lrank[k], 1);
          packed[lbase[k] + r] = ((d1.x & (DPB - 1)) << 20) | s1.x; }
        { int k = d1.y >> BIN_SHIFT, r = atomicAdd(&lrank[k], 1);
          packed[lbase[k] + r] = ((d1.y & (DPB - 1)) << 20) | s1.y; }
        { int k = d1.z >> BIN_SHIFT, r = atomicAdd(&lrank[k], 1);
          packed[lbase[k] + r] = ((d1.z & (DPB - 1)) << 20) | s1.z; }
        { int k = d1.w >> BIN_SHIFT, r = atomicAdd(&lrank[k], 1);
          packed[lbase[k] + r] = ((d1.w & (DPB - 1)) << 20) | s1.w; }
    } else {
        for (int kk = 0; kk < 8; ++kk) {
            int i = i0 + kk;
            if (i < n) {
                int d = edst[i];
                int k = d >> BIN_SHIFT;
                int r = atomicAdd(&lrank[k], 1);
                packed[lbase[k] + r] = ((d & (DPB - 1)) << 20) | esrc[i];
            }
        }
    }
}

// ---- phase 4 (NEW): per-bin LDS counting sort -> dst-sorted list + offsets ----
// block = bin, 256 threads, 2KB LDS. All rank atomics are on-CU LDS ints.
__global__ void bin_sort_kernel(const int* __restrict__ packed,
                                const int* __restrict__ binOff,
                                int* __restrict__ sorted_src,
                                int* __restrict__ offsets,
                                int nbins, int n_dst, int n_edges) {
    __shared__ int cnt[DPB];
    __shared__ int base[DPB];
    int t = threadIdx.x;        // 256 threads == DPB
    int b = blockIdx.x;
    int start = binOff[b];
    int end = binOff[b + 1];

    cnt[t] = 0;
    __syncthreads();
    // A: histogram of local dst
    for (int j = start + t; j < end; j += DPB) {
        atomicAdd(&cnt[(packed[j] >> 20) & (DPB - 1)], 1);
    }
    __syncthreads();
    // B: exclusive scan of the 256 counters (Hillis-Steele)
    int v = cnt[t];
    base[t] = v;
    __syncthreads();
    for (int o = 1; o < DPB; o <<= 1) {
        int u = (t >= o) ? base[t - o] : 0;
        __syncthreads();
        base[t] += u;
        __syncthreads();
    }
    int my_excl = base[t] - v;           // exclusive prefix for dst t
    __syncthreads();
    base[t] = my_excl;                   // publish exclusive bases
    cnt[t] = 0;                          // reset for ranking
    // global absolute offset for dst (b<<8)+t
    int g = (b << BIN_SHIFT) + t;
    if (g < n_dst) offsets[g] = start + my_excl;
    if (b == nbins - 1 && t == 0) offsets[n_dst] = n_edges;
    __syncthreads();
    // C: rank via LDS return-atomics; emit dst-sorted source indices
    for (int j = start + t; j < end; j += DPB) {
        int p = packed[j];
        int dl = (p >> 20) & (DPB - 1);
        int r = atomicAdd(&cnt[dl], 1);
        sorted_src[start + base[dl] + r] = p & 0xFFFFF;
    }
}

// ---- phase 5: parallel bf16 accum, absolute offsets (proven R12 shape) ----
__global__ void accum_abs_bf16(const uint4* __restrict__ srcb,
                               const int* __restrict__ offsets,
                               const int* __restrict__ sorted_src,
                               float4* __restrict__ out4, int n_dst) {
    int node = blockIdx.x * (blockDim.x >> 6) + (threadIdx.x >> 6);
    if (node >= n_dst) return;
    int lane = threadIdx.x & 63;
    int g = lane >> 3;
    int q = lane & 7;

    int start = offsets[node];
    int end = offsets[node + 1];

    float a0 = 0.f, a1 = 0.f, a2 = 0.f, a3 = 0.f;
    float a4 = 0.f, a5 = 0.f, a6 = 0.f, a7 = 0.f;

    for (int j = start + g; j < end; j += 8) {
        int s = sorted_src[j];
        uint4 v = srcb[(size_t)s * 8 + q];
        a0 += __uint_as_float(v.x << 16);
        a1 += __uint_as_float(v.x & 0xFFFF0000u);
        a2 += __uint_as_float(v.y << 16);
        a3 += __uint_as_float(v.y & 0xFFFF0000u);
        a4 += __uint_as_float(v.z << 16);
        a5 += __uint_as_float(v.z & 0xFFFF0000u);
        a6 += __uint_as_float(v.w << 16);
        a7 += __uint_as_float(v.w & 0xFFFF0000u);
    }

#pragma unroll
    for (int off = 8; off < 64; off <<= 1) {    // uniform across the wave
        a0 += __shfl_xor(a0, off);
        a1 += __shfl_xor(a1, off);
        a2 += __shfl_xor(a2, off);
        a3 += __shfl_xor(a3, off);
        a4 += __shfl_xor(a4, off);
        a5 += __shfl_xor(a5, off);
        a6 += __shfl_xor(a6, off);
        a7 += __shfl_xor(a7, off);
    }
    if (g == 0) {
        size_t o = (size_t)node * 16 + q * 2;
        out4[o]     = make_float4(a0, a1, a2, a3);
        out4[o + 1] = make_float4(a4, a5, a6, a7);
    }
}

// ============== tier-1: proven R13 bucket pipeline (104.5us) ==============

__global__ void fused_bucket_convert(const float4* __restrict__ src4,
                                     uint4* __restrict__ srcb, long n8,
                                     const int* __restrict__ esrc,
                                     const int* __restrict__ edst,
                                     int* __restrict__ cnt,
                                     int* __restrict__ bucket, int cap,
                                     int2* __restrict__ spill,
                                     int* __restrict__ spill_cnt, int spill_max,
                                     int n_edges) {
    int i = blockIdx.x * blockDim.x + threadIdx.x;

    int s = 0, r = 0, d = 0;
    bool have_edge = (i < n_edges);
    if (have_edge) {
        d = edst[i];
        s = esrc[i];
        r = atomicAdd(&cnt[d], 1);
    }

    long nthreads = (long)gridDim.x * blockDim.x;
    for (long t = i; t < n8; t += nthreads) {
        float4 a = src4[t * 2];
        float4 b = src4[t * 2 + 1];
        uint4 o;
        o.x = pack2(a.x, a.y);
        o.y = pack2(a.z, a.w);
        o.z = pack2(b.x, b.y);
        o.w = pack2(b.z, b.w);
        srcb[t] = o;
    }

    if (have_edge) {
        if (r < cap) {
            bucket[(size_t)d * cap + r] = s;
        } else {
            int k = atomicAdd(spill_cnt, 1);
            if (k < spill_max) spill[k] = make_int2(s, d);
        }
    }
}

__global__ void accum_bucket_bf16(const uint4* __restrict__ srcb,
                                  const int* __restrict__ cnt,
                                  const int* __restrict__ bucket, int cap,
                                  float4* __restrict__ out4, int n_dst) {
    int node = blockIdx.x * (blockDim.x >> 6) + (threadIdx.x >> 6);
    if (node >= n_dst) return;
    int lane = threadIdx.x & 63;
    int g = lane >> 3;
    int q = lane & 7;

    int cn = cnt[node];
    cn = cn < cap ? cn : cap;
    const int* brow = bucket + (size_t)node * cap;

    float a0 = 0.f, a1 = 0.f, a2 = 0.f, a3 = 0.f;
    float a4 = 0.f, a5 = 0.f, a6 = 0.f, a7 = 0.f;

    for (int j = g; j < cn; j += 8) {
        int s = brow[j];
        uint4 v = srcb[(size_t)s * 8 + q];
        a0 += __uint_as_float(v.x << 16);
        a1 += __uint_as_float(v.x & 0xFFFF0000u);
        a2 += __uint_as_float(v.y << 16);
        a3 += __uint_as_float(v.y & 0xFFFF0000u);
        a4 += __uint_as_float(v.z << 16);
        a5 += __uint_as_float(v.z & 0xFFFF0000u);
        a6 += __uint_as_float(v.w << 16);
        a7 += __uint_as_float(v.w & 0xFFFF0000u);
    }

#pragma unroll
    for (int off = 8; off < 64; off <<= 1) {
        a0 += __shfl_xor(a0, off);
        a1 += __shfl_xor(a1, off);
        a2 += __shfl_xor(a2, off);
        a3 += __shfl_xor(a3, off);
        a4 += __shfl_xor(a4, off);
        a5 += __shfl_xor(a5, off);
        a6 += __shfl_xor(a6, off);
        a7 += __shfl_xor(a7, off);
    }
    if (g == 0) {
        size_t o = (size_t)node * 16 + q * 2;
        out4[o]     = make_float4(a0, a1, a2, a3);
        out4[o + 1] = make_float4(a4, a5, a6, a7);
    }
}

__global__ void spill_add_kernel(const float* __restrict__ src_emb,
                                 const int2* __restrict__ spill,
                                 const int* __restrict__ spill_cnt,
                                 int spill_max, float* __restrict__ out) {
    int n = *spill_cnt;
    if (n > spill_max) n = spill_max;
    long total = (long)n * 16;
    long stride = (long)gridDim.x * blockDim.x;
    for (long u = (long)blockIdx.x * blockDim.x + threadIdx.x; u < total;
         u += stride) {
        int e = (int)(u >> 4);
        int q = (int)(u & 15);
        int2 p = spill[e];
        const float* row = src_emb + (size_t)p.x * 64 + q * 4;
        float* orow = out + (size_t)p.y * 64 + q * 4;
        atomicAdd(orow + 0, row[0]);
        atomicAdd(orow + 1, row[1]);
        atomicAdd(orow + 2, row[2]);
        atomicAdd(orow + 3, row[3]);
    }
}

__global__ void atomic_scatter_kernel(const float* __restrict__ src_emb,
                                      const int* __restrict__ esrc,
                                      const int* __restrict__ edst,
                                      float* __restrict__ out, int n_edges) {
    int tid = blockIdx.x * blockDim.x + threadIdx.x;
    int e = tid >> 4;
    int q = tid & 15;
    if (e >= n_edges) return;
    int s = esrc[e];
    int d = edst[e];
    const float4* srow = reinterpret_cast<const float4*>(src_emb);
    float4 v = srow[(size_t)s * 16 + q];
    float* orow = out + (size_t)d * 64 + (size_t)q * 4;
    atomicAdd(orow + 0, v.x);
    atomicAdd(orow + 1, v.y);
    atomicAdd(orow + 2, v.z);
    atomicAdd(orow + 3, v.w);
}

extern "C" void kernel_launch(void* const* d_in, const int* in_sizes, int n_in,
                              void* d_out, int out_size, void* d_ws, size_t ws_size,
                              hipStream_t stream) {
    const float* src_emb = (const float*)d_in[0];
    const int* edge_src  = (const int*)d_in[1];
    const int* edge_dst  = (const int*)d_in[2];
    float* out = (float*)d_out;

    const int n_edges = in_sizes[1];
    const int n_src   = in_sizes[0] / 64;
    const int n_dst   = out_size / 64;

    const int B = 256;
    long n8 = (long)n_src * 8;
    size_t ws_ints = ws_size / sizeof(int);

    // ---------- tier-0: bin sort pipeline ----------
    // ints: srcb[n_src*32] | binOff[nbins+1] | cursor[nbins] |
    //       packed[E] | offsets[n_dst+1] | sorted_src[E]
    {
        int nbins = (n_dst + DPB - 1) >> BIN_SHIFT;
        size_t srcb_ints = (size_t)n_src * 32;
        size_t need0 = srcb_ints + (size_t)nbins + 1 + nbins +
                       (size_t)n_edges + (size_t)n_dst + 1 + (size_t)n_edges;
        if (n_dst > 0 && n_edges > 0 && n_src > 0 && n_src <= (1 << 20) &&
            nbins >= 1 && nbins <= 1024 && ws_ints >= need0) {
            uint4* srcb     = (uint4*)d_ws;
            int* binOff     = (int*)d_ws + srcb_ints;      // [nbins+1]
            int* cursor     = binOff + nbins + 1;          // [nbins]
            int* packed     = cursor + nbins;              // [n_edges]
            int* offsets    = packed + n_edges;            // [n_dst+1]
            int* sorted_src = offsets + n_dst + 1;         // [n_edges]

            int eblocks = (n_edges + EPB - 1) / EPB;
            int nodes_per_block = B / 64;
            int agrid = (n_dst + nodes_per_block - 1) / nodes_per_block;

            convert_bf16_kernel<<<(int)((n8 + B - 1) / B), B, 0, stream>>>(
                reinterpret_cast<const float4*>(src_emb), srcb, n8);
            hipMemsetAsync(binOff, 0, ((size_t)nbins + 1) * sizeof(int), stream);
            bin_hist_kernel<<<eblocks, 512, 0, stream>>>(edge_dst, binOff,
                                                         nbins, n_edges);
            bin_scan_kernel<<<1, 1024, 0, stream>>>(binOff, cursor, nbins);
            bin_scatter_kernel<<<eblocks, 512, 0, stream>>>(edge_src, edge_dst,
                                                            cursor, packed,
                                                            nbins, n_edges);
            bin_sort_kernel<<<nbins, DPB, 0, stream>>>(packed, binOff,
                                                       sorted_src, offsets,
                                                       nbins, n_dst, n_edges);
            accum_abs_bf16<<<agrid, B, 0, stream>>>(
                srcb, offsets, sorted_src,
                reinterpret_cast<float4*>(out), n_dst);
            return;
        }
    }

    // ---------- tier-1: proven R13 bucket pipeline ----------
    if (n_dst > 0 && n_src > 0 && n_edges > 0) {
        size_t srcb_ints  = (size_t)n_src * 32;
        size_t cnt_ints   = ((size_t)n_dst + 1 + 1) & ~(size_t)1;
        int spill_entries = n_edges < 262144 ? n_edges : 262144;
        size_t spill_ints = 2 * (size_t)spill_entries;
        size_t fixed = srcb_ints + cnt_ints + spill_ints;
        if (ws_ints > fixed) {
            long cap_l = (long)((ws_ints - fixed) / (size_t)n_dst);
            cap_l &= ~1L;
            int cap = cap_l > 64 ? 64 : (int)cap_l;
            if (cap >= 24) {
                uint4* srcb    = (uint4*)d_ws;
                int* cnt       = (int*)d_ws + srcb_ints;
                int* spill_cnt = cnt + n_dst;
                int* bucket    = (int*)d_ws + srcb_ints + cnt_ints;
                int2* spill    = (int2*)(bucket + (size_t)n_dst * cap);

                int egrid1 = (n_edges + B - 1) / B;
                int nodes_per_block = B / 64;
                int agrid = (n_dst + nodes_per_block - 1) / nodes_per_block;

                hipMemsetAsync(cnt, 0, ((size_t)n_dst + 1) * sizeof(int), stream);
                fused_bucket_convert<<<egrid1, B, 0, stream>>>(
                    reinterpret_cast<const float4*>(src_emb), srcb, n8,
                    edge_src, edge_dst, cnt, bucket, cap,
                    spill, spill_cnt, spill_entries, n_edges);
                accum_bucket_bf16<<<agrid, B, 0, stream>>>(
                    srcb, cnt, bucket, cap,
                    reinterpret_cast<float4*>(out), n_dst);
                spill_add_kernel<<<16, B, 0, stream>>>(
                    src_emb, spill, spill_cnt, spill_entries, out);
                return;
            }
        }
    }

    // ---------- tier-2: direct atomic fallback ----------
    hipMemsetAsync(d_out, 0, (size_t)out_size * sizeof(float), stream);
    int total = n_edges * 16;
    atomic_scatter_kernel<<<(total + 255) / 256, 256, 0, stream>>>(
        src_emb, edge_src, edge_dst, out, n_edges);
}

// Round 16
// 71.528 us; speedup vs baseline: 6.5634x; 1.1382x over previous
//
#include <hip/hip_runtime.h>

// HeteroConv copy_u + segment_sum.
// Ladder: 858 -> 81.4us (R15). Facts: per-edge return-atomics = flat ~23G/s
// (43us/M) -- eliminated in R15 via bin front-end + LDS ranking; accum is
// gather-traffic-bound (~26us at bf16); R14 lesson: never serialize accum
// into few blocks. R16 (this): fixed-stride bins kill bin_hist+bin_scan+
// memset (their only job was bin bases): cursor[b]=b*cap, scatter reserves
// ranges as before, overflow -> exact spill list. bf16 convert fused into
// the scatter (R13-proven overlap). Sort stages bin in dynamic LDS and
// writes sorted result IN-PLACE over packed (no 2nd edge buffer).

#define DPB 256          // dsts per bin
#define BIN_SHIFT 8
#define EPB 4096         // edges per scatter block (512 thr x 8)

__device__ __forceinline__ unsigned short f2bf(float f) {
    unsigned u = __float_as_uint(f);
    unsigned r = u + 0x7FFFu + ((u >> 16) & 1u);   // round-to-nearest-even
    return (unsigned short)(r >> 16);
}
__device__ __forceinline__ unsigned pack2(float lo, float hi) {
    return (unsigned)f2bf(lo) | ((unsigned)f2bf(hi) << 16);
}

// ---- tier-0 phase 0: init cursors to fixed bin bases ----
__global__ void init_cursor_kernel(int* __restrict__ cursor,
                                   int* __restrict__ spill_cnt,
                                   int nbins, int cap) {
    int b = blockIdx.x * blockDim.x + threadIdx.x;
    if (b < nbins) cursor[b] = b * cap;
    if (b == 0) *spill_cnt = 0;
}

// ---- tier-0 phase 1: fused bin-scatter + bf16 convert ----
// LDS hist -> one return-atomic per (block,bin) range reservation; the
// grid-strided convert runs between the reservation atomics and their use,
// hiding their latency. Per-edge ranks come from LDS atomics. Overflow
// positions (pos >= (k+1)*cap) go to the spill list.
__global__ void scatter_convert_kernel(const float4* __restrict__ src4,
                                       uint4* __restrict__ srcb, long n8,
                                       const int* __restrict__ esrc,
                                       const int* __restrict__ edst,
                                       int* __restrict__ cursor,
                                       int* __restrict__ packed, int cap,
                                       int2* __restrict__ spill,
                                       int* __restrict__ spill_cnt,
                                       int spill_max, int nbins, int n) {
    __shared__ int lc[1024];
    __shared__ int lbase[1024];
    __shared__ int lrank[1024];
    int t = threadIdx.x;
    for (int k = t; k < nbins; k += blockDim.x) { lc[k] = 0; lrank[k] = 0; }
    __syncthreads();

    int i0 = blockIdx.x * EPB + t * 8;
    bool fast = (i0 + 7 < n);

    if (fast) {
        int4 d0 = *reinterpret_cast<const int4*>(edst + i0);
        int4 d1 = *reinterpret_cast<const int4*>(edst + i0 + 4);
        atomicAdd(&lc[d0.x >> BIN_SHIFT], 1);
        atomicAdd(&lc[d0.y >> BIN_SHIFT], 1);
        atomicAdd(&lc[d0.z >> BIN_SHIFT], 1);
        atomicAdd(&lc[d0.w >> BIN_SHIFT], 1);
        atomicAdd(&lc[d1.x >> BIN_SHIFT], 1);
        atomicAdd(&lc[d1.y >> BIN_SHIFT], 1);
        atomicAdd(&lc[d1.z >> BIN_SHIFT], 1);
        atomicAdd(&lc[d1.w >> BIN_SHIFT], 1);
    } else {
        for (int k = 0; k < 8; ++k) {
            int i = i0 + k;
            if (i < n) atomicAdd(&lc[edst[i] >> BIN_SHIFT], 1);
        }
    }
    __syncthreads();

    // reserve ranges (return atomics, ~nbins per block total device-wide small)
    for (int k = t; k < nbins; k += blockDim.x) {
        int c = lc[k];
        if (c > 0) lbase[k] = atomicAdd(&cursor[k], c);
    }

    // fused bf16 convert: independent streaming work hides atomic latency
    long nthreads = (long)gridDim.x * blockDim.x;
    for (long u = (long)blockIdx.x * blockDim.x + t; u < n8; u += nthreads) {
        float4 a = src4[u * 2];
        float4 b = src4[u * 2 + 1];
        uint4 o;
        o.x = pack2(a.x, a.y);
        o.y = pack2(a.z, a.w);
        o.z = pack2(b.x, b.y);
        o.w = pack2(b.z, b.w);
        srcb[u] = o;
    }
    __syncthreads();

    if (fast) {
        int4 s0 = *reinterpret_cast<const int4*>(esrc + i0);
        int4 s1 = *reinterpret_cast<const int4*>(esrc + i0 + 4);
        int4 d0 = *reinterpret_cast<const int4*>(edst + i0);
        int4 d1 = *reinterpret_cast<const int4*>(edst + i0 + 4);
        int dd[8] = {d0.x, d0.y, d0.z, d0.w, d1.x, d1.y, d1.z, d1.w};
        int ss[8] = {s0.x, s0.y, s0.z, s0.w, s1.x, s1.y, s1.z, s1.w};
#pragma unroll
        for (int e = 0; e < 8; ++e) {
            int d = dd[e], s = ss[e];
            int k = d >> BIN_SHIFT;
            int r = atomicAdd(&lrank[k], 1);
            int pos = lbase[k] + r;
            if (pos < (k + 1) * cap) {
                packed[pos] = ((d & (DPB - 1)) << 20) | s;
            } else {
                int sp = atomicAdd(spill_cnt, 1);
                if (sp < spill_max) spill[sp] = make_int2(s, d);
            }
        }
    } else {
        for (int kk = 0; kk < 8; ++kk) {
            int i = i0 + kk;
            if (i < n) {
                int d = edst[i], s = esrc[i];
                int k = d >> BIN_SHIFT;
                int r = atomicAdd(&lrank[k], 1);
                int pos = lbase[k] + r;
                if (pos < (k + 1) * cap) {
                    packed[pos] = ((d & (DPB - 1)) << 20) | s;
                } else {
                    int sp = atomicAdd(spill_cnt, 1);
                    if (sp < spill_max) spill[sp] = make_int2(s, d);
                }
            }
        }
    }
}

// ---- tier-0 phase 2: per-bin LDS counting sort, in-place over packed ----
// block = bin, 256 threads, dynamic LDS: buf[cap] + cnt[256] + base[256].
// Stages the bin in LDS, so the sorted write-back to the SAME global region
// is hazard-free. All rank atomics are on-CU LDS ints.
__global__ void bin_sort_lds_kernel(int* __restrict__ packed,
                                    const int* __restrict__ cursor,
                                    int* __restrict__ offsets,
                                    int* __restrict__ ends,
                                    int cap, int nbins, int n_dst) {
    extern __shared__ int smem[];
    int* buf  = smem;          // [cap]
    int* cnt  = smem + cap;    // [256]
    int* base = cnt + DPB;     // [256]
    int t = threadIdx.x;
    int b = blockIdx.x;
    int start = b * cap;
    int count = cursor[b] - start;
    if (count > cap) count = cap;
    if (count < 0) count = 0;

    for (int j = t; j < count; j += DPB) buf[j] = packed[start + j];
    cnt[t] = 0;
    __syncthreads();

    for (int j = t; j < count; j += DPB)
        atomicAdd(&cnt[(buf[j] >> 20) & (DPB - 1)], 1);
    __syncthreads();

    int v = cnt[t];
    base[t] = v;
    __syncthreads();
    for (int o = 1; o < DPB; o <<= 1) {
        int u = (t >= o) ? base[t - o] : 0;
        __syncthreads();
        base[t] += u;
        __syncthreads();
    }
    int excl = base[t] - v;
    __syncthreads();
    base[t] = excl;
    cnt[t] = 0;
    int g = (b << BIN_SHIFT) + t;
    if (g < n_dst) {
        offsets[g] = start + excl;
        ends[g]    = start + excl + v;
    }
    __syncthreads();

    for (int j = t; j < count; j += DPB) {
        int p = buf[j];
        int dl = (p >> 20) & (DPB - 1);
        int r = atomicAdd(&cnt[dl], 1);
        packed[start + base[dl] + r] = p & 0xFFFFF;   // src index only
    }
}

// ---- tier-0 phase 3: parallel bf16 accum (proven shape; offsets+ends) ----
__global__ void accum_fix_bf16(const uint4* __restrict__ srcb,
                               const int* __restrict__ offsets,
                               const int* __restrict__ ends,
                               const int* __restrict__ sorted_src,
                               float4* __restrict__ out4, int n_dst) {
    int node = blockIdx.x * (blockDim.x >> 6) + (threadIdx.x >> 6);
    if (node >= n_dst) return;
    int lane = threadIdx.x & 63;
    int g = lane >> 3;
    int q = lane & 7;

    int start = offsets[node];
    int end = ends[node];

    float a0 = 0.f, a1 = 0.f, a2 = 0.f, a3 = 0.f;
    float a4 = 0.f, a5 = 0.f, a6 = 0.f, a7 = 0.f;

    for (int j = start + g; j < end; j += 8) {
        int s = sorted_src[j];
        uint4 v = srcb[(size_t)s * 8 + q];
        a0 += __uint_as_float(v.x << 16);
        a1 += __uint_as_float(v.x & 0xFFFF0000u);
        a2 += __uint_as_float(v.y << 16);
        a3 += __uint_as_float(v.y & 0xFFFF0000u);
        a4 += __uint_as_float(v.z << 16);
        a5 += __uint_as_float(v.z & 0xFFFF0000u);
        a6 += __uint_as_float(v.w << 16);
        a7 += __uint_as_float(v.w & 0xFFFF0000u);
    }

#pragma unroll
    for (int off = 8; off < 64; off <<= 1) {    // uniform across the wave
        a0 += __shfl_xor(a0, off);
        a1 += __shfl_xor(a1, off);
        a2 += __shfl_xor(a2, off);
        a3 += __shfl_xor(a3, off);
        a4 += __shfl_xor(a4, off);
        a5 += __shfl_xor(a5, off);
        a6 += __shfl_xor(a6, off);
        a7 += __shfl_xor(a7, off);
    }
    if (g == 0) {
        size_t o = (size_t)node * 16 + q * 2;
        out4[o]     = make_float4(a0, a1, a2, a3);
        out4[o + 1] = make_float4(a4, a5, a6, a7);
    }
}

// ---- tier-0 phase 4: apply spill edges exactly (runs AFTER accum) ----
__global__ void spill_add_kernel(const float* __restrict__ src_emb,
                                 const int2* __restrict__ spill,
                                 const int* __restrict__ spill_cnt,
                                 int spill_max, float* __restrict__ out) {
    int n = *spill_cnt;
    if (n > spill_max) n = spill_max;
    long total = (long)n * 16;
    long stride = (long)gridDim.x * blockDim.x;
    for (long u = (long)blockIdx.x * blockDim.x + threadIdx.x; u < total;
         u += stride) {
        int e = (int)(u >> 4);
        int q = (int)(u & 15);
        int2 p = spill[e];
        const float* row = src_emb + (size_t)p.x * 64 + q * 4;
        float* orow = out + (size_t)p.y * 64 + q * 4;
        atomicAdd(orow + 0, row[0]);
        atomicAdd(orow + 1, row[1]);
        atomicAdd(orow + 2, row[2]);
        atomicAdd(orow + 3, row[3]);
    }
}

// ============ tier-1: proven R15 pipeline (81.4us) ============

__global__ void convert_bf16_kernel(const float4* __restrict__ src4,
                                    uint4* __restrict__ srcb, long n8) {
    long t = (long)blockIdx.x * blockDim.x + threadIdx.x;
    if (t >= n8) return;
    float4 a = src4[t * 2];
    float4 b = src4[t * 2 + 1];
    uint4 o;
    o.x = pack2(a.x, a.y);
    o.y = pack2(a.z, a.w);
    o.z = pack2(b.x, b.y);
    o.w = pack2(b.z, b.w);
    srcb[t] = o;
}

__global__ void bin_hist_kernel(const int* __restrict__ edst,
                                int* __restrict__ binCounts,
                                int nbins, int n) {
    __shared__ int lc[1024];
    int t = threadIdx.x;
    for (int k = t; k < nbins; k += blockDim.x) lc[k] = 0;
    __syncthreads();
    int i0 = blockIdx.x * EPB + t * 8;
    if (i0 + 7 < n) {
        int4 d0 = *reinterpret_cast<const int4*>(edst + i0);
        int4 d1 = *reinterpret_cast<const int4*>(edst + i0 + 4);
        atomicAdd(&lc[d0.x >> BIN_SHIFT], 1);
        atomicAdd(&lc[d0.y >> BIN_SHIFT], 1);
        atomicAdd(&lc[d0.z >> BIN_SHIFT], 1);
        atomicAdd(&lc[d0.w >> BIN_SHIFT], 1);
        atomicAdd(&lc[d1.x >> BIN_SHIFT], 1);
        atomicAdd(&lc[d1.y >> BIN_SHIFT], 1);
        atomicAdd(&lc[d1.z >> BIN_SHIFT], 1);
        atomicAdd(&lc[d1.w >> BIN_SHIFT], 1);
    } else {
        for (int k = 0; k < 8; ++k) {
            int i = i0 + k;
            if (i < n) atomicAdd(&lc[edst[i] >> BIN_SHIFT], 1);
        }
    }
    __syncthreads();
    for (int k = t; k < nbins; k += blockDim.x) {
        int c = lc[k];
        if (c > 0) atomicAdd(&binCounts[k], c);
    }
}

__global__ void bin_scan_kernel(int* __restrict__ binOff,
                                int* __restrict__ cursor, int nbins) {
    __shared__ int lds[1024];
    int t = threadIdx.x;
    int v = (t < nbins) ? binOff[t] : 0;
    lds[t] = v;
    __syncthreads();
    for (int off = 1; off < 1024; off <<= 1) {
        int u = (t >= off) ? lds[t - off] : 0;
        __syncthreads();
        lds[t] += u;
        __syncthreads();
    }
    if (t < nbins) {
        int base = lds[t] - v;
        binOff[t] = base;
        cursor[t] = base;
    }
    if (t == 1023) binOff[nbins] = lds[t];
}

__global__ void bin_scatter_kernel(const int* __restrict__ esrc,
                                   const int* __restrict__ edst,
                                   int* __restrict__ cursor,
                                   int* __restrict__ packed,
                                   int nbins, int n) {
    __shared__ int lc[1024];
    __shared__ int lbase[1024];
    __shared__ int lrank[1024];
    int t = threadIdx.x;
    for (int k = t; k < nbins; k += blockDim.x) { lc[k] = 0; lrank[k] = 0; }
    __syncthreads();
    int i0 = blockIdx.x * EPB + t * 8;
    bool fast = (i0 + 7 < n);
    if (fast) {
        int4 d0 = *reinterpret_cast<const int4*>(edst + i0);
        int4 d1 = *reinterpret_cast<const int4*>(edst + i0 + 4);
        atomicAdd(&lc[d0.x >> BIN_SHIFT], 1);
        atomicAdd(&lc[d0.y >> BIN_SHIFT], 1);
        atomicAdd(&lc[d0.z >> BIN_SHIFT], 1);
        atomicAdd(&lc[d0.w >> BIN_SHIFT], 1);
        atomicAdd(&lc[d1.x >> BIN_SHIFT], 1);
        atomicAdd(&lc[d1.y >> BIN_SHIFT], 1);
        atomicAdd(&lc[d1.z >> BIN_SHIFT], 1);
        atomicAdd(&lc[d1.w >> BIN_SHIFT], 1);
    } else {
        for (int k = 0; k < 8; ++k) {
            int i = i0 + k;
            if (i < n) atomicAdd(&lc[edst[i] >> BIN_SHIFT], 1);
        }
    }
    __syncthreads();
    for (int k = t; k < nbins; k += blockDim.x) {
        int c = lc[k];
        if (c > 0) lbase[k] = atomicAdd(&cursor[k], c);
    }
    __syncthreads();
    if (fast) {
        int4 s0 = *reinterpret_cast<const int4*>(esrc + i0);
        int4 s1 = *reinterpret_cast<const int4*>(esrc + i0 + 4);
        int4 d0 = *reinterpret_cast<const int4*>(edst + i0);
        int4 d1 = *reinterpret_cast<const int4*>(edst + i0 + 4);
        int dd[8] = {d0.x, d0.y, d0.z, d0.w, d1.x, d1.y, d1.z, d1.w};
        int ss[8] = {s0.x, s0.y, s0.z, s0.w, s1.x, s1.y, s1.z, s1.w};
#pragma unroll
        for (int e = 0; e < 8; ++e) {
            int k = dd[e] >> BIN_SHIFT;
            int r = atomicAdd(&lrank[k], 1);
            packed[lbase[k] + r] = ((dd[e] & (DPB - 1)) << 20) | ss[e];
        }
    } else {
        for (int kk = 0; kk < 8; ++kk) {
            int i = i0 + kk;
            if (i < n) {
                int d = edst[i];
                int k = d >> BIN_SHIFT;
                int r = atomicAdd(&lrank[k], 1);
                packed[lbase[k] + r] = ((d & (DPB - 1)) << 20) | esrc[i];
            }
        }
    }
}

__global__ void bin_sort_kernel(const int* __restrict__ packed,
                                const int* __restrict__ binOff,
                                int* __restrict__ sorted_src,
                                int* __restrict__ offsets,
                                int nbins, int n_dst, int n_edges) {
    __shared__ int cnt[DPB];
    __shared__ int base[DPB];
    int t = threadIdx.x;
    int b = blockIdx.x;
    int start = binOff[b];
    int end = binOff[b + 1];
    cnt[t] = 0;
    __syncthreads();
    for (int j = start + t; j < end; j += DPB)
        atomicAdd(&cnt[(packed[j] >> 20) & (DPB - 1)], 1);
    __syncthreads();
    int v = cnt[t];
    base[t] = v;
    __syncthreads();
    for (int o = 1; o < DPB; o <<= 1) {
        int u = (t >= o) ? base[t - o] : 0;
        __syncthreads();
        base[t] += u;
        __syncthreads();
    }
    int my_excl = base[t] - v;
    __syncthreads();
    base[t] = my_excl;
    cnt[t] = 0;
    int g = (b << BIN_SHIFT) + t;
    if (g < n_dst) offsets[g] = start + my_excl;
    if (b == nbins - 1 && t == 0) offsets[n_dst] = n_edges;
    __syncthreads();
    for (int j = start + t; j < end; j += DPB) {
        int p = packed[j];
        int dl = (p >> 20) & (DPB - 1);
        int r = atomicAdd(&cnt[dl], 1);
        sorted_src[start + base[dl] + r] = p & 0xFFFFF;
    }
}

__global__ void accum_abs_bf16(const uint4* __restrict__ srcb,
                               const int* __restrict__ offsets,
                               const int* __restrict__ sorted_src,
                               float4* __restrict__ out4, int n_dst) {
    int node = blockIdx.x * (blockDim.x >> 6) + (threadIdx.x >> 6);
    if (node >= n_dst) return;
    int lane = threadIdx.x & 63;
    int g = lane >> 3;
    int q = lane & 7;
    int start = offsets[node];
    int end = offsets[node + 1];
    float a0 = 0.f, a1 = 0.f, a2 = 0.f, a3 = 0.f;
    float a4 = 0.f, a5 = 0.f, a6 = 0.f, a7 = 0.f;
    for (int j = start + g; j < end; j += 8) {
        int s = sorted_src[j];
        uint4 v = srcb[(size_t)s * 8 + q];
        a0 += __uint_as_float(v.x << 16);
        a1 += __uint_as_float(v.x & 0xFFFF0000u);
        a2 += __uint_as_float(v.y << 16);
        a3 += __uint_as_float(v.y & 0xFFFF0000u);
        a4 += __uint_as_float(v.z << 16);
        a5 += __uint_as_float(v.z & 0xFFFF0000u);
        a6 += __uint_as_float(v.w << 16);
        a7 += __uint_as_float(v.w & 0xFFFF0000u);
    }
#pragma unroll
    for (int off = 8; off < 64; off <<= 1) {
        a0 += __shfl_xor(a0, off);
        a1 += __shfl_xor(a1, off);
        a2 += __shfl_xor(a2, off);
        a3 += __shfl_xor(a3, off);
        a4 += __shfl_xor(a4, off);
        a5 += __shfl_xor(a5, off);
        a6 += __shfl_xor(a6, off);
        a7 += __shfl_xor(a7, off);
    }
    if (g == 0) {
        size_t o = (size_t)node * 16 + q * 2;
        out4[o]     = make_float4(a0, a1, a2, a3);
        out4[o + 1] = make_float4(a4, a5, a6, a7);
    }
}

__global__ void atomic_scatter_kernel(const float* __restrict__ src_emb,
                                      const int* __restrict__ esrc,
                                      const int* __restrict__ edst,
                                      float* __restrict__ out, int n_edges) {
    int tid = blockIdx.x * blockDim.x + threadIdx.x;
    int e = tid >> 4;
    int q = tid & 15;
    if (e >= n_edges) return;
    int s = esrc[e];
    int d = edst[e];
    const float4* srow = reinterpret_cast<const float4*>(src_emb);
    float4 v = srow[(size_t)s * 16 + q];
    float* orow = out + (size_t)d * 64 + (size_t)q * 4;
    atomicAdd(orow + 0, v.x);
    atomicAdd(orow + 1, v.y);
    atomicAdd(orow + 2, v.z);
    atomicAdd(orow + 3, v.w);
}

extern "C" void kernel_launch(void* const* d_in, const int* in_sizes, int n_in,
                              void* d_out, int out_size, void* d_ws, size_t ws_size,
                              hipStream_t stream) {
    const float* src_emb = (const float*)d_in[0];
    const int* edge_src  = (const int*)d_in[1];
    const int* edge_dst  = (const int*)d_in[2];
    float* out = (float*)d_out;

    const int n_edges = in_sizes[1];
    const int n_src   = in_sizes[0] / 64;
    const int n_dst   = out_size / 64;

    const int B = 256;
    long n8 = (long)n_src * 8;
    size_t ws_ints = ws_size / sizeof(int);
    int nbins = (n_dst + DPB - 1) >> BIN_SHIFT;
    int eblocks = (n_edges + EPB - 1) / EPB;
    int nodes_per_block = B / 64;
    int agrid = (n_dst + nodes_per_block - 1) / nodes_per_block;

    // ---------- tier-0: fixed-stride bins, fused convert, in-place sort ----
    // ints: srcb[n_src*32] | cursor[nbins] | spill_cnt[1] | offsets[n_dst] |
    //       ends[n_dst] | spill[2*spill_max] | packed[nbins*cap]
    if (n_dst > 0 && n_edges > 0 && n_src > 0 && n_src <= (1 << 20) &&
        nbins >= 1 && nbins <= 1024) {
        size_t srcb_ints = (size_t)n_src * 32;
        int spill_max = 65536;
        size_t fixed = srcb_ints + nbins + 1 + 2 * (size_t)n_dst +
                       2 * (size_t)spill_max;
        if (ws_ints > fixed) {
            long cap_l = (long)((ws_ints - fixed) / (size_t)nbins);
            int cap = cap_l > 8192 ? 8192 : (int)cap_l;
            // need cap comfortably > avg bin load (E/nbins + 10 sigma)
            long avg = (long)n_edges / nbins;
            if (cap >= 3072 && (long)cap >= avg + 512 &&
                (size_t)(cap + 2 * DPB) * 4 <= 64 * 1024) {
                uint4* srcb    = (uint4*)d_ws;
                int* cursor    = (int*)d_ws + srcb_ints;     // [nbins]
                int* spill_cnt = cursor + nbins;             // [1]
                int* offsets   = spill_cnt + 1;              // [n_dst]
                int* ends      = offsets + n_dst;            // [n_dst]
                int2* spill    = (int2*)(ends + n_dst);      // [spill_max]
                int* packed    = (int*)(spill + spill_max);  // [nbins*cap]

                init_cursor_kernel<<<(nbins + B - 1) / B, B, 0, stream>>>(
                    cursor, spill_cnt, nbins, cap);
                scatter_convert_kernel<<<eblocks, 512, 0, stream>>>(
                    reinterpret_cast<const float4*>(src_emb), srcb, n8,
                    edge_src, edge_dst, cursor, packed, cap,
                    spill, spill_cnt, spill_max, nbins, n_edges);
                size_t shmem = (size_t)(cap + 2 * DPB) * sizeof(int);
                bin_sort_lds_kernel<<<nbins, DPB, shmem, stream>>>(
                    packed, cursor, offsets, ends, cap, nbins, n_dst);
                accum_fix_bf16<<<agrid, B, 0, stream>>>(
                    srcb, offsets, ends, packed,
                    reinterpret_cast<float4*>(out), n_dst);
                spill_add_kernel<<<16, B, 0, stream>>>(
                    src_emb, spill, spill_cnt, spill_max, out);
                return;
            }
        }
    }

    // ---------- tier-1: proven R15 pipeline (81.4us) ----------
    {
        size_t srcb_ints = (size_t)n_src * 32;
        size_t need1 = srcb_ints + (size_t)nbins + 1 + nbins +
                       (size_t)n_edges + (size_t)n_dst + 1 + (size_t)n_edges;
        if (n_dst > 0 && n_edges > 0 && n_src > 0 && n_src <= (1 << 20) &&
            nbins >= 1 && nbins <= 1024 && ws_ints >= need1) {
            uint4* srcb     = (uint4*)d_ws;
            int* binOff     = (int*)d_ws + srcb_ints;
            int* cursor     = binOff + nbins + 1;
            int* packed     = cursor + nbins;
            int* offsets    = packed + n_edges;
            int* sorted_src = offsets + n_dst + 1;

            convert_bf16_kernel<<<(int)((n8 + B - 1) / B), B, 0, stream>>>(
                reinterpret_cast<const float4*>(src_emb), srcb, n8);
            hipMemsetAsync(binOff, 0, ((size_t)nbins + 1) * sizeof(int), stream);
            bin_hist_kernel<<<eblocks, 512, 0, stream>>>(edge_dst, binOff,
                                                         nbins, n_edges);
            bin_scan_kernel<<<1, 1024, 0, stream>>>(binOff, cursor, nbins);
            bin_scatter_kernel<<<eblocks, 512, 0, stream>>>(edge_src, edge_dst,
                                                            cursor, packed,
                                                            nbins, n_edges);
            bin_sort_kernel<<<nbins, DPB, 0, stream>>>(packed, binOff,
                                                       sorted_src, offsets,
                                                       nbins, n_dst, n_edges);
            accum_abs_bf16<<<agrid, B, 0, stream>>>(
                srcb, offsets, sorted_src,
                reinterpret_cast<float4*>(out), n_dst);
            return;
        }
    }

    // ---------- tier-2: direct atomic fallback ----------
    hipMemsetAsync(d_out, 0, (size_t)out_size * sizeof(float), stream);
    int total = n_edges * 16;
    atomic_scatter_kernel<<<(total + 255) / 256, 256, 0, stream>>>(
        src_emb, edge_src, edge_dst, out, n_edges);
}